// Round 8
// baseline (174.770 us; speedup 1.0000x reference)
//
#include <hip/hip_runtime.h>

#define D 64
#define CAP 896          // bucket capacity: mean 640 (Poisson), +10 sigma
#define CNTB 512         // bin count/emit blocks
#define GEMMB 768        // gemm blocks in fused kernel
#define BINCH 1600       // LDS histogram chunk (>= nbk for N=100000)

typedef unsigned short u16;
typedef __attribute__((ext_vector_type(8))) __bf16 bf16x8;
typedef __attribute__((ext_vector_type(4))) float f32x4;

__device__ __forceinline__ float lrelu(float x) { return x > 0.f ? x : 0.2f * x; }
__device__ __forceinline__ u16 f2bf(float f) {           // RNE fp32 -> bf16
    unsigned u = __float_as_uint(f);
    return (u16)((u + 0x7fffu + ((u >> 16) & 1u)) >> 16);
}
__device__ __forceinline__ unsigned pack2(float lo, float hi) {
    return (unsigned)f2bf(lo) | ((unsigned)f2bf(hi) << 16);
}
__device__ __forceinline__ float blo(unsigned u) { return __uint_as_float(u << 16); }
__device__ __forceinline__ float bhi(unsigned u) { return __uint_as_float(u & 0xffff0000u); }

struct alignas(16) SG { u16 Xb[64][72]; float wsd[4][64]; };

// Phase 1: blocks [0,CNTB) = per-segment bucket COUNT (LDS hist -> transposed
// cm[bucket*CNTB+blk]); block CNTB = W pre-transpose + wsd precompute.
// NOTE: cooperative-kernel fusion of these phases (round 7) failed — plain
// stores across grid.sync() are not reliably visible cross-XCD (G16).
// Separate launches are the correctness boundary.
__global__ __launch_bounds__(256) void k_cnt(
    const int* __restrict__ dst, u16* __restrict__ cm, int E, int nbk, int Eseg,
    const float* __restrict__ W0, const float* __restrict__ as0, const float* __restrict__ ad0,
    const float* __restrict__ W1, const float* __restrict__ as1, const float* __restrict__ ad1,
    u16* __restrict__ Wt, float* __restrict__ wsd_g)
{
    __shared__ int cnt_l[BINCH];
    const int tid = threadIdx.x;

    if (blockIdx.x >= CNTB) {
        // ---- W transpose + wsd (one block) ----
        for (int i = tid; i < 4096; i += 256) {
            const int k = i >> 6, n = i & 63;
            Wt[(n << 6) + k]        = f2bf(W0[i]);
            Wt[4096 + (n << 6) + k] = f2bf(W1[i]);
        }
        const int k = tid & 63;
        const int v = tid >> 6;
        const float* Ws = (v < 2) ? W0 : W1;
        const float* av = (v == 0) ? as0 : (v == 1) ? ad0 : (v == 2) ? as1 : ad1;
        float q = 0.f;
        for (int n = 0; n < 64; ++n) q = fmaf(Ws[(k << 6) + n], av[n], q);
        wsd_g[(v << 6) + k] = q;
        return;
    }

    const int blk = blockIdx.x;
    const long e0 = (long)blk * Eseg;
    const long e1 = min(e0 + (long)Eseg, (long)E);
    for (int base = 0; base < nbk; base += BINCH) {
        const int lim = min(BINCH, nbk - base);
        for (int i = tid; i < lim; i += 256) cnt_l[i] = 0;
        __syncthreads();
        long i = e0 + tid;
        for (; i + 256 * 7 < e1; i += 256 * 8) {
            int d8[8];
#pragma unroll
            for (int k = 0; k < 8; ++k) d8[k] = dst[i + 256 * k];
#pragma unroll
            for (int k = 0; k < 8; ++k) {
                const int bb = (d8[k] >> 6) - base;
                if ((unsigned)bb < (unsigned)lim) atomicAdd(&cnt_l[bb], 1);
            }
        }
        for (; i < e1; i += 256) {
            const int bb = (dst[i] >> 6) - base;
            if ((unsigned)bb < (unsigned)lim) atomicAdd(&cnt_l[bb], 1);
        }
        __syncthreads();
        for (int j = tid; j < lim; j += 256)
            cm[(size_t)(base + j) * CNTB + blk] = (u16)cnt_l[j];
        __syncthreads();
    }
}

// Wave-parallel exclusive prefix: one wave per bucket. Each lane loads 8
// consecutive u16 counts (dwordx4, fully coalesced over the bucket's 1KB
// row), in-lane prefix + 6-step wave scan, stores offsets back in place.
__global__ __launch_bounds__(256) void k_off(
    u16* __restrict__ cm, int* __restrict__ bktcnt, int nbk)
{
    const int lane = threadIdx.x & 63;
    const int j = blockIdx.x * 4 + (threadIdx.x >> 6);
    if (j >= nbk) return;

    const uint4 u = *(const uint4*)(cm + (size_t)j * CNTB + (lane << 3));
    int c[8] = { (int)(u.x & 0xffff), (int)(u.x >> 16),
                 (int)(u.y & 0xffff), (int)(u.y >> 16),
                 (int)(u.z & 0xffff), (int)(u.z >> 16),
                 (int)(u.w & 0xffff), (int)(u.w >> 16) };
    int e[8]; int run = 0;
#pragma unroll
    for (int k = 0; k < 8; ++k) { e[k] = run; run += c[k]; }
    int incl = run;
#pragma unroll
    for (int o = 1; o < 64; o <<= 1) {
        const int t = __shfl_up(incl, o, 64);
        if (lane >= o) incl += t;
    }
    const int excl = incl - run;
#pragma unroll
    for (int k = 0; k < 8; ++k) e[k] += excl;

    uint4 o4;
    o4.x = (unsigned)(e[0] & 0xffff) | ((unsigned)(e[1] & 0xffff) << 16);
    o4.y = (unsigned)(e[2] & 0xffff) | ((unsigned)(e[3] & 0xffff) << 16);
    o4.z = (unsigned)(e[4] & 0xffff) | ((unsigned)(e[5] & 0xffff) << 16);
    o4.w = (unsigned)(e[6] & 0xffff) | ((unsigned)(e[7] & 0xffff) << 16);
    *(uint4*)(cm + (size_t)j * CNTB + (lane << 3)) = o4;

    if (lane == 63) bktcnt[j] = incl;
}

// Phase 3: blocks [0,GEMMB) = MFMA GEMM (h=x@W both branches, s/d tables),
// blocks [GEMMB, GEMMB+CNTB) = EMIT (LDS running counters seeded from the
// scanned offset column; LDS atomics only; scattered payload stores).
// Emit's latency hides under the GEMM's memory phases.
__global__ __launch_bounds__(256) void k_ge(
    const float* __restrict__ x,
    const u16* __restrict__ Wt, const float* __restrict__ wsd_g,
    u16* __restrict__ hb, float* __restrict__ s_tab, float* __restrict__ d_tab,
    int N, int ntiles,
    const int* __restrict__ src, const int* __restrict__ dst, const int* __restrict__ et,
    const u16* __restrict__ cm, unsigned* __restrict__ bkt, int E, int nbk, int Eseg)
{
    __shared__ union SM { SG g; int cnt[BINCH]; } sm;
    const int tid = threadIdx.x;

    if (blockIdx.x >= GEMMB) {
        // ---------------- emit path ----------------
        int* curl = sm.cnt;
        const int blk = blockIdx.x - GEMMB;
        const long e0 = (long)blk * Eseg;
        const long e1 = min(e0 + (long)Eseg, (long)E);

        for (int base = 0; base < nbk; base += BINCH) {
            const int lim = min(BINCH, nbk - base);
            for (int i = tid; i < lim; i += 256)
                curl[i] = (int)cm[(size_t)(base + i) * CNTB + blk];
            __syncthreads();

            long i = e0 + tid;
            for (; i + 256 * 7 < e1; i += 256 * 8) {
                int d8[8], s8[8], t8[8];
#pragma unroll
                for (int k = 0; k < 8; ++k) d8[k] = dst[i + 256 * k];
#pragma unroll
                for (int k = 0; k < 8; ++k) s8[k] = src[i + 256 * k];
#pragma unroll
                for (int k = 0; k < 8; ++k) t8[k] = et[i + 256 * k];
#pragma unroll
                for (int k = 0; k < 8; ++k) {
                    const int bb = (d8[k] >> 6) - base;
                    if ((unsigned)bb < (unsigned)lim) {
                        const int slot = atomicAdd(&curl[bb], 1);
                        if (slot < CAP)
                            bkt[(long)(base + bb) * CAP + slot] =
                                ((unsigned)(d8[k] & 63) << 18) | ((unsigned)s8[k] << 1) | (unsigned)t8[k];
                    }
                }
            }
            for (; i < e1; i += 256) {
                const int d = dst[i];
                const int bb = (d >> 6) - base;
                if ((unsigned)bb < (unsigned)lim) {
                    const int slot = atomicAdd(&curl[bb], 1);
                    if (slot < CAP)
                        bkt[(long)(base + bb) * CAP + slot] =
                            ((unsigned)(d & 63) << 18) | ((unsigned)src[i] << 1) | (unsigned)et[i];
                }
            }
            __syncthreads();
        }
        return;
    }

    // ---------------- GEMM path ----------------
    auto& Xb  = sm.g.Xb;
    auto& wsd = sm.g.wsd;

    sm.g.wsd[tid >> 6][tid & 63] = wsd_g[tid];   // coalesced, conflict-free

    const int lane = tid & 63;
    const int nl = lane & 15, quad = lane >> 4;
    const int wv = tid >> 6;

    // B-fragments straight from global Wt (L2-hot 16KB) -- no LDS staging
    bf16x8 bfrag[2][4][2];
#pragma unroll
    for (int br = 0; br < 2; ++br)
#pragma unroll
        for (int t = 0; t < 4; ++t)
#pragma unroll
            for (int h = 0; h < 2; ++h)
                bfrag[br][t][h] = *(const bf16x8*)&Wt[((br << 12) | ((t * 16 + nl) << 6)) + h * 32 + quad * 8];

    __syncthreads();

    const int rstage = tid >> 2;
    const int kc = (tid & 3) << 4;

    for (int tile = blockIdx.x; tile < ntiles; tile += GEMMB) {
        const long n0 = (long)tile << 6;
        __syncthreads();
        {
            long row = n0 + rstage; if (row >= N) row = N - 1;
            const float4* xp = (const float4*)(x + row * D + kc);
            const float4 v0 = xp[0], v1 = xp[1], v2 = xp[2], v3 = xp[3];

            unsigned q[8];
            q[0] = pack2(v0.x, v0.y); q[1] = pack2(v0.z, v0.w);
            q[2] = pack2(v1.x, v1.y); q[3] = pack2(v1.z, v1.w);
            q[4] = pack2(v2.x, v2.y); q[5] = pack2(v2.z, v2.w);
            q[6] = pack2(v3.x, v3.y); q[7] = pack2(v3.z, v3.w);
            *(uint4*)&Xb[rstage][kc]     = make_uint4(q[0], q[1], q[2], q[3]);
            *(uint4*)&Xb[rstage][kc + 8] = make_uint4(q[4], q[5], q[6], q[7]);

            float ps[4];
#pragma unroll
            for (int v = 0; v < 4; ++v) {
                const float4* wp = (const float4*)&wsd[v][kc];
                const float4 wa = wp[0], wb = wp[1], wc = wp[2], wd = wp[3];
                float s = 0.f;
                s = fmaf(v0.x, wa.x, s); s = fmaf(v0.y, wa.y, s);
                s = fmaf(v0.z, wa.z, s); s = fmaf(v0.w, wa.w, s);
                s = fmaf(v1.x, wb.x, s); s = fmaf(v1.y, wb.y, s);
                s = fmaf(v1.z, wb.z, s); s = fmaf(v1.w, wb.w, s);
                s = fmaf(v2.x, wc.x, s); s = fmaf(v2.y, wc.y, s);
                s = fmaf(v2.z, wc.z, s); s = fmaf(v2.w, wc.w, s);
                s = fmaf(v3.x, wd.x, s); s = fmaf(v3.y, wd.y, s);
                s = fmaf(v3.z, wd.z, s); s = fmaf(v3.w, wd.w, s);
                ps[v] = s;
            }
#pragma unroll
            for (int v = 0; v < 4; ++v) {
                ps[v] += __shfl_xor(ps[v], 1, 64);
                ps[v] += __shfl_xor(ps[v], 2, 64);
            }
            const long rw = n0 + rstage;
            if ((tid & 3) == 0 && rw < N) {
                s_tab[(rw << 1)]     = ps[0]; d_tab[(rw << 1)]     = ps[1];
                s_tab[(rw << 1) | 1] = ps[2]; d_tab[(rw << 1) | 1] = ps[3];
            }
        }
        __syncthreads();

        const int rbase = wv << 4;
        const bf16x8 a0 = *(const bf16x8*)&Xb[rbase + nl][quad * 8];
        const bf16x8 a1 = *(const bf16x8*)&Xb[rbase + nl][32 + quad * 8];

        f32x4 acc[2][4];
#pragma unroll
        for (int br = 0; br < 2; ++br)
#pragma unroll
            for (int t = 0; t < 4; ++t) {
                f32x4 c = {0.f, 0.f, 0.f, 0.f};
                c = __builtin_amdgcn_mfma_f32_16x16x32_bf16(a0, bfrag[br][t][0], c, 0, 0, 0);
                c = __builtin_amdgcn_mfma_f32_16x16x32_bf16(a1, bfrag[br][t][1], c, 0, 0, 0);
                acc[br][t] = c;
            }

        // permuted-coalesced store: lane nl writes cols' nl*4..nl*4+3 as uint2
#pragma unroll
        for (int reg = 0; reg < 4; ++reg) {
            const long row = n0 + rbase + (quad << 2) + reg;
            if (row < N) {
#pragma unroll
                for (int br = 0; br < 2; ++br) {
                    uint2 v;
                    v.x = pack2(acc[br][0][reg], acc[br][1][reg]);
                    v.y = pack2(acc[br][2][reg], acc[br][3][reg]);
                    *(uint2*)(hb + (((row << 1) | br) << 6) + (nl << 2)) = v;
                }
            }
        }
    }
}

// One block (512 thr) per 64-node bucket. CSR build uses ONE atomic pass:
// slot = atomicAdd(&degl[nl],1) during counting IS the within-node index;
// after the scan tokens scatter with plain stores (self-loops use fixed
// slots 0/1). Entry-parallel softmax + alpha rewrite; gather via broadcast
// ds_read_b64 of (payload, alpha).
__global__ __launch_bounds__(512) void k_proc(
    const int* __restrict__ bktcnt, const unsigned* __restrict__ bkt,
    const float* __restrict__ s_tab, const float* __restrict__ d_tab,
    const u16* __restrict__ hb,
    const float* __restrict__ b0, const float* __restrict__ b1,
    float* __restrict__ out, int N)
{
    __shared__ uint2 tok2[CAP + 128];   // .x = (nl<<18)|(src<<1)|t, .y = alpha
    __shared__ int   degl[64];
    __shared__ int   curl[64];          // exclusive-scan base per node
    __shared__ float den[128];
    __shared__ float dl[128];
    __shared__ float bsum[64];

    const int tid = threadIdx.x;
    const int b = blockIdx.x;
    const int lo = b << 6;
    const int cnt_nodes = min(64, N - lo);
    const int nb = min(bktcnt[b], CAP);

    if (tid < 64) {
        degl[tid] = (lo + tid < N) ? 2 : 0;   // slots 0,1 reserved for self-loops
        bsum[tid] = b0[tid] + b1[tid];
    }
    if (tid < 128) {
        den[tid] = 0.f;
        const int n = lo + (tid >> 1);
        dl[tid] = (n < N) ? d_tab[(n << 1) | (tid & 1)] : 0.f;
    }
    __syncthreads();

    unsigned pr[2]; int slot_r[2]; int ns = 0;
    for (int i = tid; i < nb; i += 512) {
        const unsigned p = bkt[(long)b * CAP + i];
        pr[ns] = p;
        slot_r[ns] = atomicAdd(&degl[(p >> 18) & 63], 1);   // >= 2
        ++ns;
    }
    __syncthreads();
    if (tid < 64) {
        int v = degl[tid];
        const int orig = v;
#pragma unroll
        for (int o = 1; o < 64; o <<= 1) {
            const int u = __shfl_up(v, o, 64);
            if (tid >= o) v += u;
        }
        curl[tid] = v - orig;   // exclusive prefix = segment base
    }
    __syncthreads();
    // self-loop tokens at fixed slots 0,1 (no atomics)
    if (tid < 2 * cnt_nodes) {
        const int ni = tid >> 1;
        tok2[curl[ni] + (tid & 1)].x =
            ((unsigned)ni << 18) | ((unsigned)((lo + ni) << 1)) | (unsigned)(tid & 1);
    }
    // edge tokens: plain scatter using saved slots
    for (int k = 0; k < ns; ++k) {
        const unsigned p = pr[k];
        tok2[curl[(p >> 18) & 63] + slot_r[k]].x = p;
    }
    __syncthreads();

    // entry-parallel softmax numerators + denominators
    const int T = nb + (cnt_nodes << 1);
    for (int j = tid; j < T; j += 512) {
        const unsigned u = tok2[j].x;
        const int idx = (int)(((u >> 18) << 1) | (u & 1u));
        const float e = lrelu(s_tab[u & 0x3FFFFu] + dl[idx]);
        const float p = __expf(e);
        tok2[j].y = __float_as_uint(p);
        atomicAdd(&den[idx], p);
    }
    __syncthreads();

    if (tid < 128) den[tid] = 1.f / den[tid];   // self token guarantees den>0
    __syncthreads();
    for (int j = tid; j < T; j += 512) {
        const unsigned u = tok2[j].x;
        const int idx = (int)(((u >> 18) << 1) | (u & 1u));
        tok2[j].y = __float_as_uint(__uint_as_float(tok2[j].y) * den[idx]);
    }
    __syncthreads();

    const int lane = tid & 63;
    const int wave = tid >> 6;
    const int q = lane >> 4;
    const int cl = lane & 15;

    for (int ni = wave; ni < cnt_nodes; ni += 8) {
        const int cnt = degl[ni];
        const int off = curl[ni];

        float4 acc = {0.f, 0.f, 0.f, 0.f};
        const int nq = (cnt + 3) >> 2;
        int pp = 0;
        for (; pp + 1 < nq; pp += 2) {
            const int iA = (pp << 2) + q;
            const int iB = iA + 4;
            const uint2 eA = tok2[off + iA];
            const uint2 eB = tok2[off + (iB < cnt ? iB : cnt - 1)];
            const float aA = __uint_as_float(eA.y);
            float aB = __uint_as_float(eB.y);
            if (iB >= cnt) aB = 0.f;
            const uint2 uA = *(const uint2*)(hb + ((long)(eA.x & 0x3FFFFu) << 6) + (cl << 2));
            const uint2 uB = *(const uint2*)(hb + ((long)(eB.x & 0x3FFFFu) << 6) + (cl << 2));
            acc.x = fmaf(aA, blo(uA.x), acc.x);
            acc.y = fmaf(aA, bhi(uA.x), acc.y);
            acc.z = fmaf(aA, blo(uA.y), acc.z);
            acc.w = fmaf(aA, bhi(uA.y), acc.w);
            acc.x = fmaf(aB, blo(uB.x), acc.x);
            acc.y = fmaf(aB, bhi(uB.x), acc.y);
            acc.z = fmaf(aB, blo(uB.y), acc.z);
            acc.w = fmaf(aB, bhi(uB.y), acc.w);
        }
        if (pp < nq) {
            const int iA = (pp << 2) + q;
            const uint2 eA = tok2[off + (iA < cnt ? iA : cnt - 1)];
            float aA = __uint_as_float(eA.y);
            if (iA >= cnt) aA = 0.f;
            const uint2 uA = *(const uint2*)(hb + ((long)(eA.x & 0x3FFFFu) << 6) + (cl << 2));
            acc.x = fmaf(aA, blo(uA.x), acc.x);
            acc.y = fmaf(aA, bhi(uA.x), acc.y);
            acc.z = fmaf(aA, blo(uA.y), acc.z);
            acc.w = fmaf(aA, bhi(uA.y), acc.w);
        }
        acc.x += __shfl_xor(acc.x, 16, 64);
        acc.y += __shfl_xor(acc.y, 16, 64);
        acc.z += __shfl_xor(acc.z, 16, 64);
        acc.w += __shfl_xor(acc.w, 16, 64);
        acc.x += __shfl_xor(acc.x, 32, 64);
        acc.y += __shfl_xor(acc.y, 32, 64);
        acc.z += __shfl_xor(acc.z, 32, 64);
        acc.w += __shfl_xor(acc.w, 32, 64);
        if (lane < 16) {
            float* op = out + ((long)(lo + ni) << 6);
            op[cl]      = acc.x + bsum[cl];
            op[16 + cl] = acc.y + bsum[16 + cl];
            op[32 + cl] = acc.z + bsum[32 + cl];
            op[48 + cl] = acc.w + bsum[48 + cl];
        }
    }
}

extern "C" void kernel_launch(void* const* d_in, const int* in_sizes, int n_in,
                              void* d_out, int out_size, void* d_ws, size_t ws_size,
                              hipStream_t stream) {
    const float* x   = (const float*)d_in[0];
    const int*   ei  = (const int*)d_in[1];
    const int*   et  = (const int*)d_in[2];
    const float* W0  = (const float*)d_in[3];
    const float* as0 = (const float*)d_in[4];
    const float* ad0 = (const float*)d_in[5];
    const float* b0  = (const float*)d_in[6];
    const float* W1  = (const float*)d_in[7];
    const float* as1 = (const float*)d_in[8];
    const float* ad1 = (const float*)d_in[9];
    const float* b1  = (const float*)d_in[10];
    float* out = (float*)d_out;

    const int N = in_sizes[0] / D;
    const int E = in_sizes[1] / 2;
    const int* src = ei;
    const int* dst = ei + E;

    const int nbk = (N + 63) >> 6;

    // 256B-align every carve-out (16B vector loads on Wt/cm need alignment)
    char* w = (char*)d_ws;
    auto carve = [&w](size_t bytes) {
        char* p = w;
        w += (bytes + 255) & ~(size_t)255;
        return p;
    };
    u16* hb       = (u16*)carve((size_t)2 * N * D * sizeof(u16));
    float* s_tab  = (float*)carve((size_t)2 * N * sizeof(float));
    float* d_tab  = (float*)carve((size_t)2 * N * sizeof(float));
    int* bktcnt   = (int*)carve((size_t)nbk * sizeof(int));
    unsigned* bkt = (unsigned*)carve((size_t)nbk * CAP * sizeof(unsigned));
    u16* cm       = (u16*)carve((size_t)nbk * CNTB * sizeof(u16));
    u16* Wt       = (u16*)carve((size_t)2 * 64 * 64 * sizeof(u16));
    float* wsd_g  = (float*)carve((size_t)4 * 64 * sizeof(float));

    const int ntiles = (N + 63) / 64;
    const int Eseg = (E + CNTB - 1) / CNTB;
    const int offb = (nbk + 3) / 4;

    k_cnt<<<CNTB + 1, 256, 0, stream>>>(dst, cm, E, nbk, Eseg,
                                        W0, as0, ad0, W1, as1, ad1, Wt, wsd_g);
    k_off<<<offb, 256, 0, stream>>>(cm, bktcnt, nbk);
    k_ge<<<GEMMB + CNTB, 256, 0, stream>>>(x, Wt, wsd_g,
                                           hb, s_tab, d_tab, N, ntiles,
                                           src, dst, et, cm, bkt, E, nbk, Eseg);
    k_proc<<<nbk, 512, 0, stream>>>(bktcnt, bkt, s_tab, d_tab, hb, b0, b1, out, N);
}

// Round 9
// 173.167 us; speedup vs baseline: 1.0093x; 1.0093x over previous
//
#include <hip/hip_runtime.h>

#define D 64
#define CAP 896          // bucket capacity: mean 640 (Poisson), +10 sigma
#define CNTB 512         // bin count/emit blocks
#define GEMMB 1024       // gemm blocks (more TLP for the latency-bound GEMM)
#define BINCH 1600       // LDS histogram chunk (>= nbk for N=100000)

typedef unsigned short u16;
typedef __attribute__((ext_vector_type(8))) __bf16 bf16x8;
typedef __attribute__((ext_vector_type(4))) float f32x4;

__device__ __forceinline__ float lrelu(float x) { return x > 0.f ? x : 0.2f * x; }
__device__ __forceinline__ u16 f2bf(float f) {           // RNE fp32 -> bf16
    unsigned u = __float_as_uint(f);
    return (u16)((u + 0x7fffu + ((u >> 16) & 1u)) >> 16);
}
__device__ __forceinline__ unsigned pack2(float lo, float hi) {
    return (unsigned)f2bf(lo) | ((unsigned)f2bf(hi) << 16);
}
__device__ __forceinline__ float blo(unsigned u) { return __uint_as_float(u << 16); }
__device__ __forceinline__ float bhi(unsigned u) { return __uint_as_float(u & 0xffff0000u); }

struct alignas(16) SG { u16 Xb[64][72]; float wsd[4][64]; };

// Phase 1: blocks [0,CNTB) = per-segment bucket COUNT (LDS hist -> transposed
// cm[bucket*CNTB+blk]); block CNTB = W pre-transpose + wsd precompute.
// NOTE: cooperative-kernel fusion of these phases (round 7) failed — plain
// stores across grid.sync() are not reliably visible cross-XCD (G16).
// Separate launches are the correctness boundary.
__global__ __launch_bounds__(256) void k_cnt(
    const int* __restrict__ dst, u16* __restrict__ cm, int E, int nbk, int Eseg,
    const float* __restrict__ W0, const float* __restrict__ as0, const float* __restrict__ ad0,
    const float* __restrict__ W1, const float* __restrict__ as1, const float* __restrict__ ad1,
    u16* __restrict__ Wt, float* __restrict__ wsd_g)
{
    __shared__ int cnt_l[BINCH];
    const int tid = threadIdx.x;

    if (blockIdx.x >= CNTB) {
        // ---- W transpose + wsd (one block) ----
        for (int i = tid; i < 4096; i += 256) {
            const int k = i >> 6, n = i & 63;
            Wt[(n << 6) + k]        = f2bf(W0[i]);
            Wt[4096 + (n << 6) + k] = f2bf(W1[i]);
        }
        const int k = tid & 63;
        const int v = tid >> 6;
        const float* Ws = (v < 2) ? W0 : W1;
        const float* av = (v == 0) ? as0 : (v == 1) ? ad0 : (v == 2) ? as1 : ad1;
        float q = 0.f;
        for (int n = 0; n < 64; ++n) q = fmaf(Ws[(k << 6) + n], av[n], q);
        wsd_g[(v << 6) + k] = q;
        return;
    }

    const int blk = blockIdx.x;
    const long e0 = (long)blk * Eseg;
    const long e1 = min(e0 + (long)Eseg, (long)E);
    for (int base = 0; base < nbk; base += BINCH) {
        const int lim = min(BINCH, nbk - base);
        for (int i = tid; i < lim; i += 256) cnt_l[i] = 0;
        __syncthreads();
        long i = e0 + tid;
        for (; i + 256 * 7 < e1; i += 256 * 8) {
            int d8[8];
#pragma unroll
            for (int k = 0; k < 8; ++k) d8[k] = dst[i + 256 * k];
#pragma unroll
            for (int k = 0; k < 8; ++k) {
                const int bb = (d8[k] >> 6) - base;
                if ((unsigned)bb < (unsigned)lim) atomicAdd(&cnt_l[bb], 1);
            }
        }
        for (; i < e1; i += 256) {
            const int bb = (dst[i] >> 6) - base;
            if ((unsigned)bb < (unsigned)lim) atomicAdd(&cnt_l[bb], 1);
        }
        __syncthreads();
        for (int j = tid; j < lim; j += 256)
            cm[(size_t)(base + j) * CNTB + blk] = (u16)cnt_l[j];
        __syncthreads();
    }
}

// Wave-parallel exclusive prefix: one wave per bucket. Each lane loads 8
// consecutive u16 counts (dwordx4, fully coalesced over the bucket's 1KB
// row), in-lane prefix + 6-step wave scan, stores offsets back in place.
__global__ __launch_bounds__(256) void k_off(
    u16* __restrict__ cm, int* __restrict__ bktcnt, int nbk)
{
    const int lane = threadIdx.x & 63;
    const int j = blockIdx.x * 4 + (threadIdx.x >> 6);
    if (j >= nbk) return;

    const uint4 u = *(const uint4*)(cm + (size_t)j * CNTB + (lane << 3));
    int c[8] = { (int)(u.x & 0xffff), (int)(u.x >> 16),
                 (int)(u.y & 0xffff), (int)(u.y >> 16),
                 (int)(u.z & 0xffff), (int)(u.z >> 16),
                 (int)(u.w & 0xffff), (int)(u.w >> 16) };
    int e[8]; int run = 0;
#pragma unroll
    for (int k = 0; k < 8; ++k) { e[k] = run; run += c[k]; }
    int incl = run;
#pragma unroll
    for (int o = 1; o < 64; o <<= 1) {
        const int t = __shfl_up(incl, o, 64);
        if (lane >= o) incl += t;
    }
    const int excl = incl - run;
#pragma unroll
    for (int k = 0; k < 8; ++k) e[k] += excl;

    uint4 o4;
    o4.x = (unsigned)(e[0] & 0xffff) | ((unsigned)(e[1] & 0xffff) << 16);
    o4.y = (unsigned)(e[2] & 0xffff) | ((unsigned)(e[3] & 0xffff) << 16);
    o4.z = (unsigned)(e[4] & 0xffff) | ((unsigned)(e[5] & 0xffff) << 16);
    o4.w = (unsigned)(e[6] & 0xffff) | ((unsigned)(e[7] & 0xffff) << 16);
    *(uint4*)(cm + (size_t)j * CNTB + (lane << 3)) = o4;

    if (lane == 63) bktcnt[j] = incl;
}

// Phase 3: blocks [0,GEMMB) = MFMA GEMM (h=x@W both branches, s/d tables),
// blocks [GEMMB, GEMMB+CNTB) = EMIT (LDS running counters seeded from the
// scanned offset column; LDS atomics only; scattered payload stores).
// Emit's latency hides under the GEMM's memory phases.
__global__ __launch_bounds__(256) void k_ge(
    const float* __restrict__ x,
    const u16* __restrict__ Wt, const float* __restrict__ wsd_g,
    u16* __restrict__ hb, float* __restrict__ s_tab, float* __restrict__ d_tab,
    int N, int ntiles,
    const int* __restrict__ src, const int* __restrict__ dst, const int* __restrict__ et,
    const u16* __restrict__ cm, unsigned* __restrict__ bkt, int E, int nbk, int Eseg)
{
    __shared__ union SM { SG g; int cnt[BINCH]; } sm;
    const int tid = threadIdx.x;

    if (blockIdx.x >= GEMMB) {
        // ---------------- emit path ----------------
        int* curl = sm.cnt;
        const int blk = blockIdx.x - GEMMB;
        const long e0 = (long)blk * Eseg;
        const long e1 = min(e0 + (long)Eseg, (long)E);

        for (int base = 0; base < nbk; base += BINCH) {
            const int lim = min(BINCH, nbk - base);
            for (int i = tid; i < lim; i += 256)
                curl[i] = (int)cm[(size_t)(base + i) * CNTB + blk];
            __syncthreads();

            long i = e0 + tid;
            for (; i + 256 * 7 < e1; i += 256 * 8) {
                int d8[8], s8[8], t8[8];
#pragma unroll
                for (int k = 0; k < 8; ++k) d8[k] = dst[i + 256 * k];
#pragma unroll
                for (int k = 0; k < 8; ++k) s8[k] = src[i + 256 * k];
#pragma unroll
                for (int k = 0; k < 8; ++k) t8[k] = et[i + 256 * k];
#pragma unroll
                for (int k = 0; k < 8; ++k) {
                    const int bb = (d8[k] >> 6) - base;
                    if ((unsigned)bb < (unsigned)lim) {
                        const int slot = atomicAdd(&curl[bb], 1);
                        if (slot < CAP)
                            bkt[(long)(base + bb) * CAP + slot] =
                                ((unsigned)(d8[k] & 63) << 18) | ((unsigned)s8[k] << 1) | (unsigned)t8[k];
                    }
                }
            }
            for (; i < e1; i += 256) {
                const int d = dst[i];
                const int bb = (d >> 6) - base;
                if ((unsigned)bb < (unsigned)lim) {
                    const int slot = atomicAdd(&curl[bb], 1);
                    if (slot < CAP)
                        bkt[(long)(base + bb) * CAP + slot] =
                            ((unsigned)(d & 63) << 18) | ((unsigned)src[i] << 1) | (unsigned)et[i];
                }
            }
            __syncthreads();
        }
        return;
    }

    // ---------------- GEMM path ----------------
    auto& Xb  = sm.g.Xb;
    auto& wsd = sm.g.wsd;

    sm.g.wsd[tid >> 6][tid & 63] = wsd_g[tid];   // coalesced, conflict-free

    const int lane = tid & 63;
    const int nl = lane & 15, quad = lane >> 4;
    const int wv = tid >> 6;

    // B-fragments straight from global Wt (L2-hot 16KB) -- no LDS staging
    bf16x8 bfrag[2][4][2];
#pragma unroll
    for (int br = 0; br < 2; ++br)
#pragma unroll
        for (int t = 0; t < 4; ++t)
#pragma unroll
            for (int h = 0; h < 2; ++h)
                bfrag[br][t][h] = *(const bf16x8*)&Wt[((br << 12) | ((t * 16 + nl) << 6)) + h * 32 + quad * 8];

    __syncthreads();

    const int rstage = tid >> 2;
    const int kc = (tid & 3) << 4;

    for (int tile = blockIdx.x; tile < ntiles; tile += GEMMB) {
        const long n0 = (long)tile << 6;
        __syncthreads();
        {
            long row = n0 + rstage; if (row >= N) row = N - 1;
            const float4* xp = (const float4*)(x + row * D + kc);
            const float4 v0 = xp[0], v1 = xp[1], v2 = xp[2], v3 = xp[3];

            unsigned q[8];
            q[0] = pack2(v0.x, v0.y); q[1] = pack2(v0.z, v0.w);
            q[2] = pack2(v1.x, v1.y); q[3] = pack2(v1.z, v1.w);
            q[4] = pack2(v2.x, v2.y); q[5] = pack2(v2.z, v2.w);
            q[6] = pack2(v3.x, v3.y); q[7] = pack2(v3.z, v3.w);
            *(uint4*)&Xb[rstage][kc]     = make_uint4(q[0], q[1], q[2], q[3]);
            *(uint4*)&Xb[rstage][kc + 8] = make_uint4(q[4], q[5], q[6], q[7]);

            float ps[4];
#pragma unroll
            for (int v = 0; v < 4; ++v) {
                const float4* wp = (const float4*)&wsd[v][kc];
                const float4 wa = wp[0], wb = wp[1], wc = wp[2], wd = wp[3];
                float s = 0.f;
                s = fmaf(v0.x, wa.x, s); s = fmaf(v0.y, wa.y, s);
                s = fmaf(v0.z, wa.z, s); s = fmaf(v0.w, wa.w, s);
                s = fmaf(v1.x, wb.x, s); s = fmaf(v1.y, wb.y, s);
                s = fmaf(v1.z, wb.z, s); s = fmaf(v1.w, wb.w, s);
                s = fmaf(v2.x, wc.x, s); s = fmaf(v2.y, wc.y, s);
                s = fmaf(v2.z, wc.z, s); s = fmaf(v2.w, wc.w, s);
                s = fmaf(v3.x, wd.x, s); s = fmaf(v3.y, wd.y, s);
                s = fmaf(v3.z, wd.z, s); s = fmaf(v3.w, wd.w, s);
                ps[v] = s;
            }
#pragma unroll
            for (int v = 0; v < 4; ++v) {
                ps[v] += __shfl_xor(ps[v], 1, 64);
                ps[v] += __shfl_xor(ps[v], 2, 64);
            }
            const long rw = n0 + rstage;
            if ((tid & 3) == 0 && rw < N) {
                s_tab[(rw << 1)]     = ps[0]; d_tab[(rw << 1)]     = ps[1];
                s_tab[(rw << 1) | 1] = ps[2]; d_tab[(rw << 1) | 1] = ps[3];
            }
        }
        __syncthreads();

        const int rbase = wv << 4;
        const bf16x8 a0 = *(const bf16x8*)&Xb[rbase + nl][quad * 8];
        const bf16x8 a1 = *(const bf16x8*)&Xb[rbase + nl][32 + quad * 8];

        f32x4 acc[2][4];
#pragma unroll
        for (int br = 0; br < 2; ++br)
#pragma unroll
            for (int t = 0; t < 4; ++t) {
                f32x4 c = {0.f, 0.f, 0.f, 0.f};
                c = __builtin_amdgcn_mfma_f32_16x16x32_bf16(a0, bfrag[br][t][0], c, 0, 0, 0);
                c = __builtin_amdgcn_mfma_f32_16x16x32_bf16(a1, bfrag[br][t][1], c, 0, 0, 0);
                acc[br][t] = c;
            }

        // permuted-coalesced store: lane nl writes cols' nl*4..nl*4+3 as uint2
#pragma unroll
        for (int reg = 0; reg < 4; ++reg) {
            const long row = n0 + rbase + (quad << 2) + reg;
            if (row < N) {
#pragma unroll
                for (int br = 0; br < 2; ++br) {
                    uint2 v;
                    v.x = pack2(acc[br][0][reg], acc[br][1][reg]);
                    v.y = pack2(acc[br][2][reg], acc[br][3][reg]);
                    *(uint2*)(hb + (((row << 1) | br) << 6) + (nl << 2)) = v;
                }
            }
        }
    }
}

// One block (512 thr) per 64-node bucket. One-pass CSR build, entry-parallel
// softmax + alpha rewrite. Gather restructured: each wave splits into 4x16-lane
// groups, each group OWNS one node (no cross-lane reduction, no lane masking)
// and runs a 4-deep clamped entry unroll -> 16 rows in flight per wave (2x
// the old q-interleave scheme) for the latency-bound random hb gathers.
__global__ __launch_bounds__(512) void k_proc(
    const int* __restrict__ bktcnt, const unsigned* __restrict__ bkt,
    const float* __restrict__ s_tab, const float* __restrict__ d_tab,
    const u16* __restrict__ hb,
    const float* __restrict__ b0, const float* __restrict__ b1,
    float* __restrict__ out, int N)
{
    __shared__ uint2 tok2[CAP + 128];   // .x = (nl<<18)|(src<<1)|t, .y = alpha
    __shared__ int   degl[64];
    __shared__ int   curl[64];          // exclusive-scan base per node
    __shared__ float den[128];
    __shared__ float dl[128];
    __shared__ float bsum[64];

    const int tid = threadIdx.x;
    const int b = blockIdx.x;
    const int lo = b << 6;
    const int cnt_nodes = min(64, N - lo);
    const int nb = min(bktcnt[b], CAP);

    if (tid < 64) {
        degl[tid] = (lo + tid < N) ? 2 : 0;   // slots 0,1 reserved for self-loops
        bsum[tid] = b0[tid] + b1[tid];
    }
    if (tid < 128) {
        den[tid] = 0.f;
        const int n = lo + (tid >> 1);
        dl[tid] = (n < N) ? d_tab[(n << 1) | (tid & 1)] : 0.f;
    }
    __syncthreads();

    unsigned pr[2]; int slot_r[2]; int ns = 0;
    for (int i = tid; i < nb; i += 512) {
        const unsigned p = bkt[(long)b * CAP + i];
        pr[ns] = p;
        slot_r[ns] = atomicAdd(&degl[(p >> 18) & 63], 1);   // >= 2
        ++ns;
    }
    __syncthreads();
    if (tid < 64) {
        int v = degl[tid];
        const int orig = v;
#pragma unroll
        for (int o = 1; o < 64; o <<= 1) {
            const int u = __shfl_up(v, o, 64);
            if (tid >= o) v += u;
        }
        curl[tid] = v - orig;   // exclusive prefix = segment base
    }
    __syncthreads();
    // self-loop tokens at fixed slots 0,1 (no atomics)
    if (tid < 2 * cnt_nodes) {
        const int ni = tid >> 1;
        tok2[curl[ni] + (tid & 1)].x =
            ((unsigned)ni << 18) | ((unsigned)((lo + ni) << 1)) | (unsigned)(tid & 1);
    }
    // edge tokens: plain scatter using saved slots
    for (int k = 0; k < ns; ++k) {
        const unsigned p = pr[k];
        tok2[curl[(p >> 18) & 63] + slot_r[k]].x = p;
    }
    __syncthreads();

    // entry-parallel softmax numerators + denominators
    const int T = nb + (cnt_nodes << 1);
    for (int j = tid; j < T; j += 512) {
        const unsigned u = tok2[j].x;
        const int idx = (int)(((u >> 18) << 1) | (u & 1u));
        const float e = lrelu(s_tab[u & 0x3FFFFu] + dl[idx]);
        const float p = __expf(e);
        tok2[j].y = __float_as_uint(p);
        atomicAdd(&den[idx], p);
    }
    __syncthreads();

    if (tid < 128) den[tid] = 1.f / den[tid];   // self token guarantees den>0
    __syncthreads();
    for (int j = tid; j < T; j += 512) {
        const unsigned u = tok2[j].x;
        const int idx = (int)(((u >> 18) << 1) | (u & 1u));
        tok2[j].y = __float_as_uint(__uint_as_float(tok2[j].y) * den[idx]);
    }
    __syncthreads();

    const int lane = tid & 63;
    const int wave = tid >> 6;
    const int grp = lane >> 4;        // which node this 16-lane group owns
    const int cl = lane & 15;         // reads cols' cl*4..cl*4+3

    // 8 waves x 4 groups = 32 nodes per pass; 2 passes cover the bucket
    for (int ni = (wave << 2) + grp; ni < cnt_nodes; ni += 32) {
        const int cnt = degl[ni];
        const int off = curl[ni];

        float4 acc = {0.f, 0.f, 0.f, 0.f};
        for (int j = 0; j < cnt; j += 4) {
            const int c1 = (j + 1 < cnt) ? j + 1 : cnt - 1;
            const int c2 = (j + 2 < cnt) ? j + 2 : cnt - 1;
            const int c3 = (j + 3 < cnt) ? j + 3 : cnt - 1;
            const uint2 e0 = tok2[off + j];
            const uint2 e1 = tok2[off + c1];
            const uint2 e2 = tok2[off + c2];
            const uint2 e3 = tok2[off + c3];
            const float a0 = __uint_as_float(e0.y);
            const float a1 = (j + 1 < cnt) ? __uint_as_float(e1.y) : 0.f;
            const float a2 = (j + 2 < cnt) ? __uint_as_float(e2.y) : 0.f;
            const float a3 = (j + 3 < cnt) ? __uint_as_float(e3.y) : 0.f;
            const uint2 u0 = *(const uint2*)(hb + ((long)(e0.x & 0x3FFFFu) << 6) + (cl << 2));
            const uint2 u1 = *(const uint2*)(hb + ((long)(e1.x & 0x3FFFFu) << 6) + (cl << 2));
            const uint2 u2 = *(const uint2*)(hb + ((long)(e2.x & 0x3FFFFu) << 6) + (cl << 2));
            const uint2 u3 = *(const uint2*)(hb + ((long)(e3.x & 0x3FFFFu) << 6) + (cl << 2));
            acc.x = fmaf(a0, blo(u0.x), acc.x);
            acc.y = fmaf(a0, bhi(u0.x), acc.y);
            acc.z = fmaf(a0, blo(u0.y), acc.z);
            acc.w = fmaf(a0, bhi(u0.y), acc.w);
            acc.x = fmaf(a1, blo(u1.x), acc.x);
            acc.y = fmaf(a1, bhi(u1.x), acc.y);
            acc.z = fmaf(a1, blo(u1.y), acc.z);
            acc.w = fmaf(a1, bhi(u1.y), acc.w);
            acc.x = fmaf(a2, blo(u2.x), acc.x);
            acc.y = fmaf(a2, bhi(u2.x), acc.y);
            acc.z = fmaf(a2, blo(u2.y), acc.z);
            acc.w = fmaf(a2, bhi(u2.y), acc.w);
            acc.x = fmaf(a3, blo(u3.x), acc.x);
            acc.y = fmaf(a3, bhi(u3.x), acc.y);
            acc.z = fmaf(a3, blo(u3.y), acc.z);
            acc.w = fmaf(a3, bhi(u3.y), acc.w);
        }

        float* op = out + ((long)(lo + ni) << 6);
        op[cl]      = acc.x + bsum[cl];
        op[16 + cl] = acc.y + bsum[16 + cl];
        op[32 + cl] = acc.z + bsum[32 + cl];
        op[48 + cl] = acc.w + bsum[48 + cl];
    }
}

extern "C" void kernel_launch(void* const* d_in, const int* in_sizes, int n_in,
                              void* d_out, int out_size, void* d_ws, size_t ws_size,
                              hipStream_t stream) {
    const float* x   = (const float*)d_in[0];
    const int*   ei  = (const int*)d_in[1];
    const int*   et  = (const int*)d_in[2];
    const float* W0  = (const float*)d_in[3];
    const float* as0 = (const float*)d_in[4];
    const float* ad0 = (const float*)d_in[5];
    const float* b0  = (const float*)d_in[6];
    const float* W1  = (const float*)d_in[7];
    const float* as1 = (const float*)d_in[8];
    const float* ad1 = (const float*)d_in[9];
    const float* b1  = (const float*)d_in[10];
    float* out = (float*)d_out;

    const int N = in_sizes[0] / D;
    const int E = in_sizes[1] / 2;
    const int* src = ei;
    const int* dst = ei + E;

    const int nbk = (N + 63) >> 6;

    // 256B-align every carve-out (16B vector loads on Wt/cm need alignment)
    char* w = (char*)d_ws;
    auto carve = [&w](size_t bytes) {
        char* p = w;
        w += (bytes + 255) & ~(size_t)255;
        return p;
    };
    u16* hb       = (u16*)carve((size_t)2 * N * D * sizeof(u16));
    float* s_tab  = (float*)carve((size_t)2 * N * sizeof(float));
    float* d_tab  = (float*)carve((size_t)2 * N * sizeof(float));
    int* bktcnt   = (int*)carve((size_t)nbk * sizeof(int));
    unsigned* bkt = (unsigned*)carve((size_t)nbk * CAP * sizeof(unsigned));
    u16* cm       = (u16*)carve((size_t)nbk * CNTB * sizeof(u16));
    u16* Wt       = (u16*)carve((size_t)2 * 64 * 64 * sizeof(u16));
    float* wsd_g  = (float*)carve((size_t)4 * 64 * sizeof(float));

    const int ntiles = (N + 63) / 64;
    const int Eseg = (E + CNTB - 1) / CNTB;
    const int offb = (nbk + 3) / 4;

    k_cnt<<<CNTB + 1, 256, 0, stream>>>(dst, cm, E, nbk, Eseg,
                                        W0, as0, ad0, W1, as1, ad1, Wt, wsd_g);
    k_off<<<offb, 256, 0, stream>>>(cm, bktcnt, nbk);
    k_ge<<<GEMMB + CNTB, 256, 0, stream>>>(x, Wt, wsd_g,
                                           hb, s_tab, d_tab, N, ntiles,
                                           src, dst, et, cm, bkt, E, nbk, Eseg);
    k_proc<<<nbk, 512, 0, stream>>>(bktcnt, bkt, s_tab, d_tab, hb, b0, b1, out, N);
}